// Round 1
// baseline (656.170 us; speedup 1.0000x reference)
//
#include <hip/hip_runtime.h>
#include <hip/hip_bf16.h>

#define NROWS 50000
#define CDIM 8
#define XDIM 256
#define HDIM 256

typedef __attribute__((ext_vector_type(8))) short bf16x8;  // MFMA bf16 operand (4 VGPRs)
typedef __attribute__((ext_vector_type(4))) float f32x4;   // MFMA accumulator

// fp32 -> bf16 round-to-nearest-even
__device__ __forceinline__ unsigned short f2bf_rne(float f) {
    unsigned int u = __builtin_bit_cast(unsigned int, f);
    u += 0x7fffu + ((u >> 16) & 1u);
    return (unsigned short)(u >> 16);
}

__device__ __forceinline__ bf16x8 pack8(const f32x4 a, const f32x4 b) {
    bf16x8 r;
    r[0] = (short)f2bf_rne(a[0]);
    r[1] = (short)f2bf_rne(a[1]);
    r[2] = (short)f2bf_rne(a[2]);
    r[3] = (short)f2bf_rne(a[3]);
    r[4] = (short)f2bf_rne(b[0]);
    r[5] = (short)f2bf_rne(b[1]);
    r[6] = (short)f2bf_rne(b[2]);
    r[7] = (short)f2bf_rne(b[3]);
    return r;
}

// Pack W_left / W_right / W_top (each [256,256] fp32, row-major [x][h]) into
// MFMA A-operand fragment layout in ws:
//   frag index = ((seg*8 + xc)*16 + ht), 64 lanes x 8 bf16 each (16 B/lane).
//   value[lane][j] = W_seg[ xc*32 + (lane>>4)*8 + j ][ ht*16 + (lane&15) ]
// 384 tiles * 1024 B = 384 KiB total.
__global__ __launch_bounds__(256) void pack_weights(
        const float* __restrict__ Wl, const float* __restrict__ Wr,
        const float* __restrict__ Wt, bf16x8* __restrict__ wp) {
    int t = blockIdx.x * 256 + threadIdx.x;   // 24576 threads total
    int lane = t & 63;
    int tile = t >> 6;          // 0..383
    int ht  = tile & 15;
    int sx  = tile >> 4;        // seg*8 + xc
    int xc  = sx & 7;
    int seg = sx >> 3;
    const float* __restrict__ W = (seg == 0) ? Wl : (seg == 1) ? Wr : Wt;
    int x0 = xc * 32 + (lane >> 4) * 8;
    int h  = ht * 16 + (lane & 15);
    bf16x8 frag;
#pragma unroll
    for (int j = 0; j < 8; ++j)
        frag[j] = (short)f2bf_rne(W[(size_t)(x0 + j) * HDIM + h]);
    wp[t] = frag;
}

// One wave computes out[16 rows][256 h]. Block = 4 waves = 64 rows.
// A-operand = packed weights (m = h), B-operand = activations (n = row).
// D layout (16x16, verified m89): col = lane&15 = row_local, row = quad*4+reg = h_local.
__global__ __launch_bounds__(256) void tbcnn_main(
        const float* __restrict__ child, const float* __restrict__ parent,
        const bf16x8* __restrict__ wp, const float* __restrict__ bias,
        float* __restrict__ out) {
    const int wave = threadIdx.x >> 6;
    const int lane = threadIdx.x & 63;
    const int wtask = blockIdx.x * 4 + wave;
    const int row0 = wtask * 16;
    if (row0 >= NROWS) return;            // 50000 % 16 == 0: full tiles only

    const int rmod = lane & 15;           // row_local (B-operand n / D col)
    const int quad = lane >> 4;           // k-octet selector
    const int row  = row0 + rmod;

    const float* __restrict__ chrow = child  + (size_t)row * (CDIM * XDIM);
    const float* __restrict__ prow  = parent + (size_t)row * XDIM;

    // positional tree weights, fp32 exact same constants as reference
    const float lwt[8] = {7.f/7.f, 6.f/7.f, 5.f/7.f, 4.f/7.f, 3.f/7.f, 2.f/7.f, 1.f/7.f, 0.f/7.f};
    const float rwt[8] = {0.f/7.f, 1.f/7.f, 2.f/7.f, 3.f/7.f, 4.f/7.f, 5.f/7.f, 6.f/7.f, 7.f/7.f};

    f32x4 acc[16];
#pragma unroll
    for (int t = 0; t < 16; ++t) acc[t] = (f32x4){0.f, 0.f, 0.f, 0.f};

#pragma unroll 1
    for (int xc = 0; xc < 8; ++xc) {
        const int x0 = xc * 32 + quad * 8;   // this lane's 8 x's

        // ---- compute s_left / s_right for lane's (row, 8 x's) in fp32 ----
        f32x4 sl0 = (f32x4){0.f,0.f,0.f,0.f}, sl1 = (f32x4){0.f,0.f,0.f,0.f};
        f32x4 sr0 = (f32x4){0.f,0.f,0.f,0.f}, sr1 = (f32x4){0.f,0.f,0.f,0.f};
#pragma unroll
        for (int c = 0; c < CDIM; ++c) {
            const f32x4* p = (const f32x4*)(chrow + (size_t)c * XDIM + x0);
            f32x4 a = p[0];
            f32x4 b = p[1];
            sl0 += a * lwt[c];  sl1 += b * lwt[c];
            sr0 += a * rwt[c];  sr1 += b * rwt[c];
        }
        const f32x4* pp = (const f32x4*)(prow + x0);
        f32x4 p0 = pp[0];
        f32x4 p1 = pp[1];

        // B-operand fragments: n = lane&15 = row_local, k = quad*8+j = x  (matches layout)
        bf16x8 fL = pack8(sl0, sl1);
        bf16x8 fR = pack8(sr0, sr1);
        bf16x8 fP = pack8(p0, p1);

        // ---- 3 k-steps (left / right / top), 16 h-tiles each ----
        const bf16x8* wL = wp + ((size_t)((0 * 8 + xc) * 16)) * 64 + lane;
        const bf16x8* wR = wp + ((size_t)((1 * 8 + xc) * 16)) * 64 + lane;
        const bf16x8* wT = wp + ((size_t)((2 * 8 + xc) * 16)) * 64 + lane;
#pragma unroll
        for (int ht = 0; ht < 16; ++ht)
            acc[ht] = __builtin_amdgcn_mfma_f32_16x16x32_bf16(wL[ht * 64], fL, acc[ht], 0, 0, 0);
#pragma unroll
        for (int ht = 0; ht < 16; ++ht)
            acc[ht] = __builtin_amdgcn_mfma_f32_16x16x32_bf16(wR[ht * 64], fR, acc[ht], 0, 0, 0);
#pragma unroll
        for (int ht = 0; ht < 16; ++ht)
            acc[ht] = __builtin_amdgcn_mfma_f32_16x16x32_bf16(wT[ht * 64], fP, acc[ht], 0, 0, 0);
    }

    // ---- epilogue: bias + relu, float4 stores (4 consecutive h per tile) ----
    float* __restrict__ orow = out + (size_t)row * HDIM;   // D col = lane&15 = row_local
#pragma unroll
    for (int ht = 0; ht < 16; ++ht) {
        const int h = ht * 16 + quad * 4;
        f32x4 b4 = *(const f32x4*)(bias + h);
        f32x4 v = acc[ht];
        v[0] = fmaxf(v[0] + b4[0], 0.f);
        v[1] = fmaxf(v[1] + b4[1], 0.f);
        v[2] = fmaxf(v[2] + b4[2], 0.f);
        v[3] = fmaxf(v[3] + b4[3], 0.f);
        *(f32x4*)(orow + h) = v;
    }
}

// Correct-but-slow fallback if ws is too small for the packed weights.
__global__ __launch_bounds__(256) void tbcnn_fallback(
        const float* __restrict__ child, const float* __restrict__ parent,
        const float* __restrict__ Wl, const float* __restrict__ Wr,
        const float* __restrict__ Wt, const float* __restrict__ bias,
        float* __restrict__ out) {
    __shared__ float sl[XDIM], sr[XDIM], sp[XDIM];
    const int n = blockIdx.x;
    const int h = threadIdx.x;
    const float lwt[8] = {7.f/7.f, 6.f/7.f, 5.f/7.f, 4.f/7.f, 3.f/7.f, 2.f/7.f, 1.f/7.f, 0.f/7.f};
    const float* ch = child + (size_t)n * (CDIM * XDIM);
    float al = 0.f, ar = 0.f;
#pragma unroll
    for (int c = 0; c < CDIM; ++c) {
        float v = ch[c * XDIM + h];
        al += lwt[c] * v;
        ar += (1.f - lwt[c]) * v;   // rwt[c] == c/7
    }
    // recompute rwt exactly to match reference constants
    ar = 0.f;
    const float rwt[8] = {0.f/7.f, 1.f/7.f, 2.f/7.f, 3.f/7.f, 4.f/7.f, 5.f/7.f, 6.f/7.f, 7.f/7.f};
#pragma unroll
    for (int c = 0; c < CDIM; ++c) ar += rwt[c] * ch[c * XDIM + h];
    sl[h] = al; sr[h] = ar; sp[h] = parent[(size_t)n * XDIM + h];
    __syncthreads();
    float a = bias[h];
    for (int x = 0; x < XDIM; ++x)
        a += sl[x] * Wl[(size_t)x * HDIM + h] + sr[x] * Wr[(size_t)x * HDIM + h]
           + sp[x] * Wt[(size_t)x * HDIM + h];
    out[(size_t)n * HDIM + h] = fmaxf(a, 0.f);
}

extern "C" void kernel_launch(void* const* d_in, const int* in_sizes, int n_in,
                              void* d_out, int out_size, void* d_ws, size_t ws_size,
                              hipStream_t stream) {
    const float* child  = (const float*)d_in[0];
    const float* parent = (const float*)d_in[1];
    const float* Wl     = (const float*)d_in[2];
    const float* Wr     = (const float*)d_in[3];
    const float* Wt     = (const float*)d_in[4];
    const float* bias   = (const float*)d_in[5];
    float* out = (float*)d_out;

    const size_t wp_bytes = (size_t)3 * XDIM * HDIM * sizeof(unsigned short); // 384 KiB
    if (ws_size >= wp_bytes) {
        bf16x8* wp = (bf16x8*)d_ws;
        pack_weights<<<96, 256, 0, stream>>>(Wl, Wr, Wt, wp);
        const int n_wtasks = NROWS / 16;                 // 3125
        const int n_blocks = (n_wtasks + 3) / 4;         // 782
        tbcnn_main<<<n_blocks, 256, 0, stream>>>(child, parent, wp, bias, out);
    } else {
        tbcnn_fallback<<<NROWS, 256, 0, stream>>>(child, parent, Wl, Wr, Wt, bias, out);
    }
}